// Round 8
// baseline (386.140 us; speedup 1.0000x reference)
//
#include <hip/hip_runtime.h>
#include <math.h>

// out[c,i] = W[i]^2 * sum_{e: iInd[e]=i} x[c, jInd[e]]   (B=1, C=32)
//
// Pipeline:
//  1. transpose x [C,N] -> xtb [N,C] in BF16 (3.2MB, L2-resident; one
//     record's 32-channel row = one 64B line).
//  2. bin_edges: LDS-staged binning of (i&127,j) records into NB buckets,
//     coalesced run flushes.
//  3. accumulate4: ONE 1024-thread block per bucket (exclusive owner).
//     Lane-per-record: coalesced rec loads, 4x uint4 row loads, unpack,
//     32 LDS atomic adds. Flush = plain coalesced `out += W^2 * acc`
//     (6.4MB total, no partial slab, no reduce kernel, no f32 atomics).

#define TCH 32
#define BSHIFT 7
#define BNODES 128
#define MAXNB 512
#define SLOTS 32
#define BIN_THREADS 512
#define TILE 4096
#define EPT (TILE / BIN_THREADS)
#define ACC_THREADS 1024

__device__ __forceinline__ unsigned short f32_to_bf16(float f) {
    unsigned int u = __float_as_uint(f);
    unsigned int r = (u + 0x7FFFu + ((u >> 16) & 1u)) >> 16;
    return (unsigned short)r;
}

__global__ void transpose_CN_to_NC_bf16(const float* __restrict__ x,
                                        unsigned short* __restrict__ xtb,
                                        int N) {
    __shared__ float tile[32][33];
    const int n0 = blockIdx.x * 32;
    const int tx = threadIdx.x;
    const int ty = threadIdx.y;
    const int n = n0 + tx;
    if (n < N) tile[ty][tx] = x[(size_t)ty * N + n];
    __syncthreads();
    const int nw = n0 + ty;
    if (nw < N) xtb[(size_t)nw * TCH + tx] = f32_to_bf16(tile[tx][ty]);
}

__device__ __forceinline__ void direct_update(float* out, const float* W,
                                              const float* x, int i, int j,
                                              int N) {
    const float w = W[i];
    const float w2 = w * w;
    for (int c = 0; c < TCH; ++c)
        atomicAdd(&out[(size_t)c * N + i], w2 * x[(size_t)c * N + j]);
}

__global__ __launch_bounds__(BIN_THREADS) void bin_edges(
    const int* __restrict__ iInd, const int* __restrict__ jInd,
    const float* __restrict__ W, const float* __restrict__ x,
    int* __restrict__ bins, int* __restrict__ gcursor,
    float* __restrict__ out, int E, int N, int NB, int cap) {
    __shared__ int stage[MAXNB * SLOTS];  // 64 KB
    __shared__ int scnt[MAXNB];
    __shared__ int incl[MAXNB];
    __shared__ int cntA[MAXNB];
    __shared__ int gbase[MAXNB];
    const int tid = threadIdx.x;

    scnt[tid] = 0;  // BIN_THREADS == MAXNB
    __syncthreads();

    const int e0 = blockIdx.x * TILE;
    for (int s = 0; s < EPT; ++s) {
        const int e = e0 + s * BIN_THREADS + tid;
        if (e < E) {
            const int i = iInd[e];
            const int j = jInd[e];
            const int b = i >> BSHIFT;
            const int slot = atomicAdd(&scnt[b], 1);
            if (slot < SLOTS) {
                stage[b * SLOTS + slot] = ((i & (BNODES - 1)) << 16) | j;
            } else {
                direct_update(out, W, x, i, j, N);  // ultra-rare
            }
        }
    }
    __syncthreads();

    int c_b = (tid < NB) ? min(scnt[tid], SLOTS) : 0;
    cntA[tid] = c_b;
    incl[tid] = c_b;
    __syncthreads();
    for (int off = 1; off < MAXNB; off <<= 1) {
        const int v = (tid >= off) ? incl[tid - off] : 0;
        __syncthreads();
        incl[tid] += v;
        __syncthreads();
    }
    if (tid < NB && c_b > 0) gbase[tid] = atomicAdd(&gcursor[tid], c_b);
    __syncthreads();

    const int total = incl[MAXNB - 1];
    for (int idx = tid; idx < total; idx += BIN_THREADS) {
        int lo = 0, hi = MAXNB - 1;
        while (lo < hi) {
            const int mid = (lo + hi) >> 1;
            if (incl[mid] > idx) hi = mid; else lo = mid + 1;
        }
        const int b = lo;
        const int k = idx - (incl[b] - cntA[b]);
        const int rec = stage[b * SLOTS + k];
        const int gslot = gbase[b] + k;
        if (gslot < cap) {
            bins[(size_t)b * cap + gslot] = rec;
        } else {
            const int i = (b << BSHIFT) | (rec >> 16);
            direct_update(out, W, x, i, rec & 0xFFFF, N);  // ultra-rare
        }
    }
}

// One 1024-thread block per bucket (exclusive owner). Lane-per-record.
__global__ __launch_bounds__(ACC_THREADS) void accumulate4(
    const int* __restrict__ bins, const int* __restrict__ gcursor,
    const unsigned short* __restrict__ xtb, const float* __restrict__ W,
    float* __restrict__ out, int N, int cap) {
    const int bucket = blockIdx.x;
    __shared__ float acc[BNODES * 33];
    for (int k = threadIdx.x; k < BNODES * 33; k += ACC_THREADS) acc[k] = 0.f;
    __syncthreads();

    int cnt = gcursor[bucket];
    if (cnt > cap) cnt = cap;
    const int* rec = bins + (size_t)bucket * cap;

    for (int r = threadIdx.x; r < cnt; r += ACC_THREADS) {
        const int pr = rec[r];                    // coalesced
        const int j  = pr & 0xFFFF;
        const int il = pr >> 16;
        const uint4* row = (const uint4*)(xtb + (size_t)j * TCH);
        const uint4 q0 = row[0];
        const uint4 q1 = row[1];
        const uint4 q2 = row[2];
        const uint4 q3 = row[3];
        float* a = &acc[il * 33];
        const unsigned int ws[16] = {q0.x, q0.y, q0.z, q0.w,
                                     q1.x, q1.y, q1.z, q1.w,
                                     q2.x, q2.y, q2.z, q2.w,
                                     q3.x, q3.y, q3.z, q3.w};
#pragma unroll
        for (int w = 0; w < 16; ++w) {
            const unsigned int u = ws[w];
            atomicAdd(&a[2 * w + 0], __uint_as_float(u << 16));
            atomicAdd(&a[2 * w + 1], __uint_as_float(u & 0xFFFF0000u));
        }
    }
    __syncthreads();

    // Exclusive-owner coalesced flush: out[c, i0..i0+127] += w^2 * acc
    const int i0 = bucket << BSHIFT;
    for (int k = threadIdx.x; k < BNODES * TCH; k += ACC_THREADS) {
        const int il = k & (BNODES - 1);
        const int cc = k >> BSHIFT;
        const int i = i0 + il;
        if (i < N) {
            const float w = W[i];
            out[(size_t)cc * N + i] += w * w * acc[il * 33 + cc];
        }
    }
}

// ---- fallback (ws too small / N too big for record packing) ----
__global__ void edge_scatter_cn(const int* __restrict__ iInd,
                                const int* __restrict__ jInd,
                                const float* __restrict__ W,
                                const float* __restrict__ x,
                                float* __restrict__ out, int E, int N) {
    const long long t = (long long)blockIdx.x * blockDim.x + threadIdx.x;
    const int e = (int)(t >> 5);
    const int c = (int)(t & 31);
    if (e < E) {
        const int i = iInd[e];
        const int j = jInd[e];
        const float w = W[i];
        atomicAdd(&out[(size_t)c * N + i], w * w * x[(size_t)c * N + j]);
    }
}

extern "C" void kernel_launch(void* const* d_in, const int* in_sizes, int n_in,
                              void* d_out, int out_size, void* d_ws, size_t ws_size,
                              hipStream_t stream) {
    const float* x    = (const float*)d_in[0];   // [1, C, N]
    const float* W    = (const float*)d_in[1];   // [N]
    const int*   iInd = (const int*)d_in[2];     // [E]
    const int*   jInd = (const int*)d_in[3];     // [E]

    const int N = in_sizes[1];
    const int E = in_sizes[2];
    float* out = (float*)d_out;

    const int NB = (N + BNODES - 1) >> BSHIFT;
    const int mean = (NB > 0) ? (E / NB) : 0;
    const int cap = mean + (int)(8.0 * sqrt((double)(mean > 0 ? mean : 1))) + 64;

    // byte-layout in ws, 256B-aligned sections
    const size_t A = 256;
    const size_t xtb_bytes = (((size_t)N * TCH * 2) + A - 1) / A * A;
    const size_t bin_bytes = (((size_t)NB * cap * 4) + A - 1) / A * A;
    const size_t cur_bytes = (((size_t)NB * 4) + A - 1) / A * A;
    const size_t base_need = xtb_bytes + bin_bytes + cur_bytes;

    if (ws_size >= base_need && NB <= MAXNB && N <= 65536) {
        char* wsb = (char*)d_ws;
        unsigned short* xtb = (unsigned short*)wsb;
        int*   bins    = (int*)(wsb + xtb_bytes);
        int*   gcursor = (int*)(wsb + xtb_bytes + bin_bytes);

        hipMemsetAsync(out, 0, (size_t)out_size * sizeof(float), stream);
        hipMemsetAsync(gcursor, 0, (size_t)NB * sizeof(int), stream);

        const int ntiles = (N + 31) / 32;
        dim3 tb(32, 32);
        transpose_CN_to_NC_bf16<<<ntiles, tb, 0, stream>>>(x, xtb, N);

        const int bin_blocks = (E + TILE - 1) / TILE;
        bin_edges<<<bin_blocks, BIN_THREADS, 0, stream>>>(
            iInd, jInd, W, x, bins, gcursor, out, E, N, NB, cap);

        accumulate4<<<NB, ACC_THREADS, 0, stream>>>(
            bins, gcursor, xtb, W, out, N, cap);
    } else {
        hipMemsetAsync(out, 0, (size_t)out_size * sizeof(float), stream);
        const int threads = 256;
        const long long total = (long long)E * TCH;
        const int blocks = (int)((total + threads - 1) / threads);
        edge_scatter_cn<<<blocks, threads, 0, stream>>>(iInd, jInd, W, x, out, E, N);
    }
}

// Round 9
// 82.106 us; speedup vs baseline: 4.7029x; 4.7029x over previous
//
#include <hip/hip_runtime.h>
#include <math.h>

// out[c,i] = W[i]^2 * sum_{e: iInd[e]=i} x[c, jInd[e]]   (B=1, C=32)
//
// Pipeline:
//  1. transpose x [C,N] -> xtb [N,C] in BF16 (3.2MB, L2-resident).
//  2. bin_edges: LDS-staged binning of (i&127,j) records into NB buckets
//     (proven ~25us). One int atomic per bucket-tile for the flush runs.
//  3. sort_reduce (NEW): per bucket: LDS counting-sort records by il
//     (histogram + scan + scatter; the ONLY LDS atomics are on 128
//     counters), then per-node REGISTER segment-sum (lane=channel,
//     4-deep unrolled bf16 gathers), one plain LDS write per node,
//     exclusive-owner coalesced flush to out. No accumulator RMW.

#define TCH 32
#define BSHIFT 7
#define BNODES 128
#define MAXNB 512
#define SLOTS 32
#define BIN_THREADS 512
#define TILE 4096
#define EPT (TILE / BIN_THREADS)
#define SR_THREADS 512
#define SJ_CAP 5120

__device__ __forceinline__ unsigned short f32_to_bf16(float f) {
    unsigned int u = __float_as_uint(f);
    unsigned int r = (u + 0x7FFFu + ((u >> 16) & 1u)) >> 16;
    return (unsigned short)r;
}
__device__ __forceinline__ float bf16_to_f32(unsigned short h) {
    return __uint_as_float(((unsigned int)h) << 16);
}

__global__ void transpose_CN_to_NC_bf16(const float* __restrict__ x,
                                        unsigned short* __restrict__ xtb,
                                        int N) {
    __shared__ float tile[32][33];
    const int n0 = blockIdx.x * 32;
    const int tx = threadIdx.x;
    const int ty = threadIdx.y;
    const int n = n0 + tx;
    if (n < N) tile[ty][tx] = x[(size_t)ty * N + n];
    __syncthreads();
    const int nw = n0 + ty;
    if (nw < N) xtb[(size_t)nw * TCH + tx] = f32_to_bf16(tile[tx][ty]);
}

__device__ __forceinline__ void direct_update(float* out, const float* W,
                                              const float* x, int i, int j,
                                              int N) {
    const float w = W[i];
    const float w2 = w * w;
    for (int c = 0; c < TCH; ++c)
        atomicAdd(&out[(size_t)c * N + i], w2 * x[(size_t)c * N + j]);
}

__global__ __launch_bounds__(BIN_THREADS) void bin_edges(
    const int* __restrict__ iInd, const int* __restrict__ jInd,
    const float* __restrict__ W, const float* __restrict__ x,
    int* __restrict__ bins, int* __restrict__ gcursor,
    float* __restrict__ out, int E, int N, int NB, int cap) {
    __shared__ int stage[MAXNB * SLOTS];  // 64 KB
    __shared__ int scnt[MAXNB];
    __shared__ int incl[MAXNB];
    __shared__ int cntA[MAXNB];
    __shared__ int gbase[MAXNB];
    const int tid = threadIdx.x;

    scnt[tid] = 0;  // BIN_THREADS == MAXNB
    __syncthreads();

    const int e0 = blockIdx.x * TILE;
    for (int s = 0; s < EPT; ++s) {
        const int e = e0 + s * BIN_THREADS + tid;
        if (e < E) {
            const int i = iInd[e];
            const int j = jInd[e];
            const int b = i >> BSHIFT;
            const int slot = atomicAdd(&scnt[b], 1);
            if (slot < SLOTS) {
                stage[b * SLOTS + slot] = ((i & (BNODES - 1)) << 16) | j;
            } else {
                direct_update(out, W, x, i, j, N);  // ultra-rare
            }
        }
    }
    __syncthreads();

    int c_b = (tid < NB) ? min(scnt[tid], SLOTS) : 0;
    cntA[tid] = c_b;
    incl[tid] = c_b;
    __syncthreads();
    for (int off = 1; off < MAXNB; off <<= 1) {
        const int v = (tid >= off) ? incl[tid - off] : 0;
        __syncthreads();
        incl[tid] += v;
        __syncthreads();
    }
    if (tid < NB && c_b > 0) gbase[tid] = atomicAdd(&gcursor[tid], c_b);
    __syncthreads();

    const int total = incl[MAXNB - 1];
    for (int idx = tid; idx < total; idx += BIN_THREADS) {
        int lo = 0, hi = MAXNB - 1;
        while (lo < hi) {
            const int mid = (lo + hi) >> 1;
            if (incl[mid] > idx) hi = mid; else lo = mid + 1;
        }
        const int b = lo;
        const int k = idx - (incl[b] - cntA[b]);
        const int rec = stage[b * SLOTS + k];
        const int gslot = gbase[b] + k;
        if (gslot < cap) {
            bins[(size_t)b * cap + gslot] = rec;
        } else {
            const int i = (b << BSHIFT) | (rec >> 16);
            direct_update(out, W, x, i, rec & 0xFFFF, N);  // ultra-rare
        }
    }
}

// One 512-thread block per bucket. Counting-sort by il, then per-node
// register segment-sum. No accumulator atomics.
__global__ __launch_bounds__(SR_THREADS) void sort_reduce(
    const int* __restrict__ bins, const int* __restrict__ gcursor,
    const unsigned short* __restrict__ xtb, const float* __restrict__ W,
    float* __restrict__ out, int N, int cap) {
    const int bucket = blockIdx.x;
    __shared__ unsigned short sj[SJ_CAP];     // sorted j per bucket
    __shared__ float acc[BNODES * 33];        // final per-bucket result
    __shared__ int hcnt[BNODES];
    __shared__ int off[BNODES + 1];
    __shared__ int cur[BNODES];

    int cnt = gcursor[bucket];
    if (cnt > cap) cnt = cap;
    const int* rec = bins + (size_t)bucket * cap;

    for (int k = threadIdx.x; k < BNODES; k += SR_THREADS) {
        hcnt[k] = 0;
        cur[k] = 0;
    }
    __syncthreads();

    // pass 1: histogram of il (LDS atomics on 128 counters only)
    for (int r = threadIdx.x; r < cnt; r += SR_THREADS)
        atomicAdd(&hcnt[rec[r] >> 16], 1);
    __syncthreads();

    // scan -> off[0..128]
    if (threadIdx.x < BNODES) off[threadIdx.x + 1] = hcnt[threadIdx.x];
    if (threadIdx.x == 0) off[0] = 0;
    __syncthreads();
    for (int d = 1; d < BNODES; d <<= 1) {
        int v = 0;
        if (threadIdx.x < BNODES && (threadIdx.x + 1) > d)
            v = off[threadIdx.x + 1 - d];
        __syncthreads();
        if (threadIdx.x < BNODES) off[threadIdx.x + 1] += v;
        __syncthreads();
    }

    // pass 2: scatter j into sorted order
    for (int r = threadIdx.x; r < cnt; r += SR_THREADS) {
        const int pr = rec[r];
        const int il = pr >> 16;
        const int pos = off[il] + atomicAdd(&cur[il], 1);
        sj[pos] = (unsigned short)(pr & 0xFFFF);
    }
    __syncthreads();

    // per-node register segment-sum: 16 groups x 32 lanes, lane=channel
    const int c = threadIdx.x & 31;
    const int g = threadIdx.x >> 5;
    for (int il = g; il < BNODES; il += SR_THREADS / 32) {
        const int beg = off[il];
        const int end = off[il + 1];
        float s0 = 0.f, s1 = 0.f, s2 = 0.f, s3 = 0.f;
        int r = beg;
        for (; r + 4 <= end; r += 4) {
            const int j0 = sj[r + 0];
            const int j1 = sj[r + 1];
            const int j2 = sj[r + 2];
            const int j3 = sj[r + 3];
            s0 += bf16_to_f32(xtb[j0 * TCH + c]);
            s1 += bf16_to_f32(xtb[j1 * TCH + c]);
            s2 += bf16_to_f32(xtb[j2 * TCH + c]);
            s3 += bf16_to_f32(xtb[j3 * TCH + c]);
        }
        for (; r < end; ++r) s0 += bf16_to_f32(xtb[sj[r] * TCH + c]);
        acc[il * 33 + c] = (s0 + s1) + (s2 + s3);  // plain write, exclusive
    }
    __syncthreads();

    // exclusive-owner coalesced flush
    const int i0 = bucket << BSHIFT;
    for (int k = threadIdx.x; k < BNODES * TCH; k += SR_THREADS) {
        const int il = k & (BNODES - 1);
        const int cc = k >> BSHIFT;
        const int i = i0 + il;
        if (i < N) {
            const float w = W[i];
            out[(size_t)cc * N + i] += w * w * acc[il * 33 + cc];
        }
    }
}

// ---- fallback (ws too small / N too big for record packing) ----
__global__ void edge_scatter_cn(const int* __restrict__ iInd,
                                const int* __restrict__ jInd,
                                const float* __restrict__ W,
                                const float* __restrict__ x,
                                float* __restrict__ out, int E, int N) {
    const long long t = (long long)blockIdx.x * blockDim.x + threadIdx.x;
    const int e = (int)(t >> 5);
    const int c = (int)(t & 31);
    if (e < E) {
        const int i = iInd[e];
        const int j = jInd[e];
        const float w = W[i];
        atomicAdd(&out[(size_t)c * N + i], w * w * x[(size_t)c * N + j]);
    }
}

extern "C" void kernel_launch(void* const* d_in, const int* in_sizes, int n_in,
                              void* d_out, int out_size, void* d_ws, size_t ws_size,
                              hipStream_t stream) {
    const float* x    = (const float*)d_in[0];   // [1, C, N]
    const float* W    = (const float*)d_in[1];   // [N]
    const int*   iInd = (const int*)d_in[2];     // [E]
    const int*   jInd = (const int*)d_in[3];     // [E]

    const int N = in_sizes[1];
    const int E = in_sizes[2];
    float* out = (float*)d_out;

    const int NB = (N + BNODES - 1) >> BSHIFT;
    const int mean = (NB > 0) ? (E / NB) : 0;
    int cap = mean + (int)(8.0 * sqrt((double)(mean > 0 ? mean : 1))) + 64;
    if (cap > SJ_CAP) cap = SJ_CAP;  // overflow -> direct_update fallback

    // byte-layout in ws, 256B-aligned sections
    const size_t A = 256;
    const size_t xtb_bytes = (((size_t)N * TCH * 2) + A - 1) / A * A;
    const size_t bin_bytes = (((size_t)NB * cap * 4) + A - 1) / A * A;
    const size_t cur_bytes = (((size_t)NB * 4) + A - 1) / A * A;
    const size_t base_need = xtb_bytes + bin_bytes + cur_bytes;

    if (ws_size >= base_need && NB <= MAXNB && N <= 65536) {
        char* wsb = (char*)d_ws;
        unsigned short* xtb = (unsigned short*)wsb;
        int*   bins    = (int*)(wsb + xtb_bytes);
        int*   gcursor = (int*)(wsb + xtb_bytes + bin_bytes);

        hipMemsetAsync(out, 0, (size_t)out_size * sizeof(float), stream);
        hipMemsetAsync(gcursor, 0, (size_t)NB * sizeof(int), stream);

        const int ntiles = (N + 31) / 32;
        dim3 tb(32, 32);
        transpose_CN_to_NC_bf16<<<ntiles, tb, 0, stream>>>(x, xtb, N);

        const int bin_blocks = (E + TILE - 1) / TILE;
        bin_edges<<<bin_blocks, BIN_THREADS, 0, stream>>>(
            iInd, jInd, W, x, bins, gcursor, out, E, N, NB, cap);

        sort_reduce<<<NB, SR_THREADS, 0, stream>>>(
            bins, gcursor, xtb, W, out, N, cap);
    } else {
        hipMemsetAsync(out, 0, (size_t)out_size * sizeof(float), stream);
        const int threads = 256;
        const long long total = (long long)E * TCH;
        const int blocks = (int)((total + threads - 1) / threads);
        edge_scatter_cn<<<blocks, threads, 0, stream>>>(iInd, jInd, W, x, out, E, N);
    }
}

// Round 10
// 76.088 us; speedup vs baseline: 5.0749x; 1.0791x over previous
//
#include <hip/hip_runtime.h>
#include <math.h>

// out[c,i] = W[i]^2 * sum_{e: iInd[e]=i} x[c, jInd[e]]   (B=1, C=32)
//
// Pipeline:
//  1. transpose x [C,N] -> xtb [N,C] in BF16 (3.2MB, L2-resident).
//  2. bin_edges: LDS-staged binning of (i&127,j) records into NB buckets.
//     Overflows append (i,j) to a global overflow list (no direct atomics).
//  3. sort_reduce2: NB*4 blocks; each owns a 32-node sub-range of one
//     bucket. LDS counting-sort of in-range records (atomics only on 32
//     counters), register segment-sum (lane=channel, 4-deep unroll),
//     PLAIN coalesced store to out (no memset, no RMW, no atomics).
//  4. overflow_apply: atomically applies the (normally empty) overflow list.

#define TCH 32
#define BSHIFT 7
#define BNODES 128
#define MAXNB 512
#define SLOTS 32
#define BIN_THREADS 512
#define TILE 4096
#define EPT (TILE / BIN_THREADS)
#define SR_THREADS 512
#define SPLIT2 4
#define NSUB (BNODES / SPLIT2)   // 32 nodes per sort_reduce2 block
#define SJ2_CAP 2048

__device__ __forceinline__ unsigned short f32_to_bf16(float f) {
    unsigned int u = __float_as_uint(f);
    unsigned int r = (u + 0x7FFFu + ((u >> 16) & 1u)) >> 16;
    return (unsigned short)r;
}
__device__ __forceinline__ float bf16_to_f32(unsigned short h) {
    return __uint_as_float(((unsigned int)h) << 16);
}

__global__ void transpose_CN_to_NC_bf16(const float* __restrict__ x,
                                        unsigned short* __restrict__ xtb,
                                        int N) {
    __shared__ float tile[32][33];
    const int n0 = blockIdx.x * 32;
    const int tx = threadIdx.x;
    const int ty = threadIdx.y;
    const int n = n0 + tx;
    if (n < N) tile[ty][tx] = x[(size_t)ty * N + n];
    __syncthreads();
    const int nw = n0 + ty;
    if (nw < N) xtb[(size_t)nw * TCH + tx] = f32_to_bf16(tile[tx][ty]);
}

__device__ __forceinline__ void push_ovf(int* ovf_cnt, int2* ovf, int ovf_cap,
                                         int i, int j) {
    const int p = atomicAdd(ovf_cnt, 1);
    if (p < ovf_cap) ovf[p] = make_int2(i, j);
}

__global__ __launch_bounds__(BIN_THREADS) void bin_edges(
    const int* __restrict__ iInd, const int* __restrict__ jInd,
    int* __restrict__ bins, int* __restrict__ gcursor,
    int* __restrict__ ovf_cnt, int2* __restrict__ ovf, int ovf_cap,
    int E, int NB, int cap) {
    __shared__ int stage[MAXNB * SLOTS];  // 64 KB
    __shared__ int scnt[MAXNB];
    __shared__ int incl[MAXNB];
    __shared__ int cntA[MAXNB];
    __shared__ int gbase[MAXNB];
    const int tid = threadIdx.x;

    scnt[tid] = 0;  // BIN_THREADS == MAXNB
    __syncthreads();

    const int e0 = blockIdx.x * TILE;
    for (int s = 0; s < EPT; ++s) {
        const int e = e0 + s * BIN_THREADS + tid;
        if (e < E) {
            const int i = iInd[e];
            const int j = jInd[e];
            const int b = i >> BSHIFT;
            const int slot = atomicAdd(&scnt[b], 1);
            if (slot < SLOTS) {
                stage[b * SLOTS + slot] = ((i & (BNODES - 1)) << 16) | j;
            } else {
                push_ovf(ovf_cnt, ovf, ovf_cap, i, j);  // ultra-rare
            }
        }
    }
    __syncthreads();

    int c_b = (tid < NB) ? min(scnt[tid], SLOTS) : 0;
    cntA[tid] = c_b;
    incl[tid] = c_b;
    __syncthreads();
    for (int off = 1; off < MAXNB; off <<= 1) {
        const int v = (tid >= off) ? incl[tid - off] : 0;
        __syncthreads();
        incl[tid] += v;
        __syncthreads();
    }
    if (tid < NB && c_b > 0) gbase[tid] = atomicAdd(&gcursor[tid], c_b);
    __syncthreads();

    const int total = incl[MAXNB - 1];
    for (int idx = tid; idx < total; idx += BIN_THREADS) {
        int lo = 0, hi = MAXNB - 1;
        while (lo < hi) {
            const int mid = (lo + hi) >> 1;
            if (incl[mid] > idx) hi = mid; else lo = mid + 1;
        }
        const int b = lo;
        const int k = idx - (incl[b] - cntA[b]);
        const int rec = stage[b * SLOTS + k];
        const int gslot = gbase[b] + k;
        if (gslot < cap) {
            bins[(size_t)b * cap + gslot] = rec;
        } else {
            push_ovf(ovf_cnt, ovf, ovf_cap,
                     (b << BSHIFT) | (rec >> 16), rec & 0xFFFF);  // ultra-rare
        }
    }
}

// NB*4 blocks; block (bucket, sub) owns nodes [sub*32, sub*32+32).
// Counting-sort in-range records, register segment-sum, plain store.
__global__ __launch_bounds__(SR_THREADS) void sort_reduce2(
    const int* __restrict__ bins, const int* __restrict__ gcursor,
    const unsigned short* __restrict__ xtb, const float* __restrict__ W,
    float* __restrict__ out, int* __restrict__ ovf_cnt,
    int2* __restrict__ ovf, int ovf_cap, int N, int cap) {
    const int bucket = blockIdx.x >> 2;
    const int sub = blockIdx.x & (SPLIT2 - 1);
    const int il0 = sub * NSUB;
    __shared__ unsigned short sj[SJ2_CAP];
    __shared__ float acc[NSUB * 33];
    __shared__ int hcnt[NSUB];
    __shared__ int off[NSUB + 1];
    __shared__ int cur[NSUB];

    int cnt = gcursor[bucket];
    if (cnt > cap) cnt = cap;
    const int* rec = bins + (size_t)bucket * cap;

    if (threadIdx.x < NSUB) { hcnt[threadIdx.x] = 0; cur[threadIdx.x] = 0; }
    __syncthreads();

    // pass 1: histogram of in-range il
    for (int r = threadIdx.x; r < cnt; r += SR_THREADS) {
        const int il = rec[r] >> 16;
        if ((il >> 5) == sub) atomicAdd(&hcnt[il & (NSUB - 1)], 1);
    }
    __syncthreads();

    if (threadIdx.x == 0) {
        int run = 0;
        for (int k = 0; k < NSUB; ++k) { off[k] = run; run += hcnt[k]; }
        off[NSUB] = run;
    }
    __syncthreads();

    // pass 2: scatter in-range j into sorted order
    for (int r = threadIdx.x; r < cnt; r += SR_THREADS) {
        const int pr = rec[r];
        const int il = pr >> 16;
        if ((il >> 5) == sub) {
            const int pos = off[il & (NSUB - 1)] +
                            atomicAdd(&cur[il & (NSUB - 1)], 1);
            if (pos < SJ2_CAP) {
                sj[pos] = (unsigned short)(pr & 0xFFFF);
            } else {
                push_ovf(ovf_cnt, ovf, ovf_cap,
                         (bucket << BSHIFT) | il, pr & 0xFFFF);  // ultra-rare
            }
        }
    }
    __syncthreads();

    // register segment-sum: 16 groups x 32 lanes, lane=channel
    const int c = threadIdx.x & 31;
    const int g = threadIdx.x >> 5;
    for (int ill = g; ill < NSUB; ill += SR_THREADS / 32) {
        const int beg = min(off[ill], SJ2_CAP);
        const int end = min(off[ill + 1], SJ2_CAP);
        float s0 = 0.f, s1 = 0.f, s2 = 0.f, s3 = 0.f;
        int r = beg;
        for (; r + 4 <= end; r += 4) {
            const int j0 = sj[r + 0];
            const int j1 = sj[r + 1];
            const int j2 = sj[r + 2];
            const int j3 = sj[r + 3];
            s0 += bf16_to_f32(xtb[j0 * TCH + c]);
            s1 += bf16_to_f32(xtb[j1 * TCH + c]);
            s2 += bf16_to_f32(xtb[j2 * TCH + c]);
            s3 += bf16_to_f32(xtb[j3 * TCH + c]);
        }
        for (; r < end; ++r) s0 += bf16_to_f32(xtb[sj[r] * TCH + c]);
        acc[ill * 33 + c] = (s0 + s1) + (s2 + s3);
    }
    __syncthreads();

    // exclusive-owner plain coalesced store
    const int i0 = (bucket << BSHIFT) + il0;
    for (int k = threadIdx.x; k < NSUB * TCH; k += SR_THREADS) {
        const int ill = k & (NSUB - 1);
        const int cc = k >> 5;
        const int i = i0 + ill;
        if (i < N) {
            const float w = W[i];
            out[(size_t)cc * N + i] = w * w * acc[ill * 33 + cc];
        }
    }
}

// applies overflow entries (normally zero) with atomics, AFTER sort_reduce2.
__global__ void overflow_apply(const int2* __restrict__ ovf,
                               const int* __restrict__ ovf_cnt,
                               const float* __restrict__ W,
                               const float* __restrict__ x,
                               float* __restrict__ out, int N, int ovf_cap) {
    int cnt = *ovf_cnt;
    if (cnt > ovf_cap) cnt = ovf_cap;
    const long long total = (long long)cnt * TCH;
    const long long stride = (long long)gridDim.x * blockDim.x;
    for (long long t = (long long)blockIdx.x * blockDim.x + threadIdx.x;
         t < total; t += stride) {
        const int e = (int)(t >> 5);
        const int c = (int)(t & 31);
        const int2 p = ovf[e];
        const float w = W[p.x];
        atomicAdd(&out[(size_t)c * N + p.x], w * w * x[(size_t)c * N + p.y]);
    }
}

// ---- fallback (ws too small / N too big for record packing) ----
__global__ void edge_scatter_cn(const int* __restrict__ iInd,
                                const int* __restrict__ jInd,
                                const float* __restrict__ W,
                                const float* __restrict__ x,
                                float* __restrict__ out, int E, int N) {
    const long long t = (long long)blockIdx.x * blockDim.x + threadIdx.x;
    const int e = (int)(t >> 5);
    const int c = (int)(t & 31);
    if (e < E) {
        const int i = iInd[e];
        const int j = jInd[e];
        const float w = W[i];
        atomicAdd(&out[(size_t)c * N + i], w * w * x[(size_t)c * N + j]);
    }
}

extern "C" void kernel_launch(void* const* d_in, const int* in_sizes, int n_in,
                              void* d_out, int out_size, void* d_ws, size_t ws_size,
                              hipStream_t stream) {
    const float* x    = (const float*)d_in[0];   // [1, C, N]
    const float* W    = (const float*)d_in[1];   // [N]
    const int*   iInd = (const int*)d_in[2];     // [E]
    const int*   jInd = (const int*)d_in[3];     // [E]

    const int N = in_sizes[1];
    const int E = in_sizes[2];
    float* out = (float*)d_out;

    const int NB = (N + BNODES - 1) >> BSHIFT;
    const int mean = (NB > 0) ? (E / NB) : 0;
    const int cap = mean + (int)(8.0 * sqrt((double)(mean > 0 ? mean : 1))) + 64;

    // ws layout (256B-aligned sections):
    //   xtb | bins | gcursor(NB)+ovf_cnt(1) | ovf entries
    const size_t A = 256;
    const size_t xtb_bytes = (((size_t)N * TCH * 2) + A - 1) / A * A;
    const size_t bin_bytes = (((size_t)NB * cap * 4) + A - 1) / A * A;
    const size_t cur_bytes = (((size_t)(NB + 1) * 4) + A - 1) / A * A;
    const size_t base_need = xtb_bytes + bin_bytes + cur_bytes;

    int ovf_cap = 0;
    if (ws_size > base_need) {
        size_t avail = ws_size - base_need;
        size_t oc = avail / sizeof(int2);
        if (oc > (size_t)(1 << 21)) oc = (size_t)(1 << 21);  // 2M entries
        ovf_cap = (int)oc;
    }

    if (ws_size >= base_need && ovf_cap >= 65536 && NB <= MAXNB && N <= 65536) {
        char* wsb = (char*)d_ws;
        unsigned short* xtb = (unsigned short*)wsb;
        int*   bins    = (int*)(wsb + xtb_bytes);
        int*   gcursor = (int*)(wsb + xtb_bytes + bin_bytes);
        int*   ovf_cnt = gcursor + NB;
        int2*  ovf     = (int2*)(wsb + base_need);

        // single small memset: gcursor + ovf_cnt contiguous
        hipMemsetAsync(gcursor, 0, (size_t)(NB + 1) * sizeof(int), stream);

        const int ntiles = (N + 31) / 32;
        dim3 tb(32, 32);
        transpose_CN_to_NC_bf16<<<ntiles, tb, 0, stream>>>(x, xtb, N);

        const int bin_blocks = (E + TILE - 1) / TILE;
        bin_edges<<<bin_blocks, BIN_THREADS, 0, stream>>>(
            iInd, jInd, bins, gcursor, ovf_cnt, ovf, ovf_cap, E, NB, cap);

        sort_reduce2<<<NB * SPLIT2, SR_THREADS, 0, stream>>>(
            bins, gcursor, xtb, W, out, ovf_cnt, ovf, ovf_cap, N, cap);

        overflow_apply<<<128, 256, 0, stream>>>(
            ovf, ovf_cnt, W, x, out, N, ovf_cap);
    } else {
        hipMemsetAsync(out, 0, (size_t)out_size * sizeof(float), stream);
        const int threads = 256;
        const long long total = (long long)E * TCH;
        const int blocks = (int)((total + threads - 1) / threads);
        edge_scatter_cn<<<blocks, threads, 0, stream>>>(iInd, jInd, W, x, out, E, N);
    }
}

// Round 11
// 65.702 us; speedup vs baseline: 5.8771x; 1.1581x over previous
//
#include <hip/hip_runtime.h>
#include <math.h>

// out[c,i] = W[i]^2 * sum_{e: iInd[e]=i} x[c, jInd[e]]   (B=1, C=32)
//
// Pipeline:
//  1. transpose x [C,N] -> xtb [N,C] in BF16 (3.2MB, L2-resident).
//  2. bin_edges: LDS-staged binning of (i&127,j) records into NB buckets,
//     int4-vectorized edge loads. Overflows -> global overflow list.
//  3. sort_reduce3: NB*4 blocks; each owns 32 nodes of one bucket.
//     LDS counting-sort of in-range records, then register segment-sum with
//     uint2-per-lane gathers (4 records per group-VMEM-instr, 8 lanes/record,
//     4 channels/lane), shfl_xor slot-combine per segment, plain coalesced
//     store to out. No accumulator RMW, no global f32 atomics.
//  4. overflow_apply: applies the (normally empty) overflow list.

#define TCH 32
#define BSHIFT 7
#define BNODES 128
#define MAXNB 512
#define SLOTS 32
#define BIN_THREADS 512
#define TILE 4096
#define SR_THREADS 512
#define SPLIT2 4
#define NSUB (BNODES / SPLIT2)   // 32 nodes per sort_reduce block
#define SJ2_CAP 2048

__device__ __forceinline__ unsigned short f32_to_bf16(float f) {
    unsigned int u = __float_as_uint(f);
    unsigned int r = (u + 0x7FFFu + ((u >> 16) & 1u)) >> 16;
    return (unsigned short)r;
}

__global__ void transpose_CN_to_NC_bf16(const float* __restrict__ x,
                                        unsigned short* __restrict__ xtb,
                                        int N) {
    __shared__ float tile[32][33];
    const int n0 = blockIdx.x * 32;
    const int tx = threadIdx.x;
    const int ty = threadIdx.y;
    const int n = n0 + tx;
    if (n < N) tile[ty][tx] = x[(size_t)ty * N + n];
    __syncthreads();
    const int nw = n0 + ty;
    if (nw < N) xtb[(size_t)nw * TCH + tx] = f32_to_bf16(tile[tx][ty]);
}

__global__ void init_counters(int* __restrict__ gcursor, int NB) {
    const int t = threadIdx.x;
    for (int k = t; k < NB + 1; k += blockDim.x) gcursor[k] = 0;
}

__device__ __forceinline__ void push_ovf(int* ovf_cnt, int2* ovf, int ovf_cap,
                                         int i, int j) {
    const int p = atomicAdd(ovf_cnt, 1);
    if (p < ovf_cap) ovf[p] = make_int2(i, j);
}

__global__ __launch_bounds__(BIN_THREADS) void bin_edges(
    const int* __restrict__ iInd, const int* __restrict__ jInd,
    int* __restrict__ bins, int* __restrict__ gcursor,
    int* __restrict__ ovf_cnt, int2* __restrict__ ovf, int ovf_cap,
    int E, int NB, int cap) {
    __shared__ int stage[MAXNB * SLOTS];  // 64 KB
    __shared__ int scnt[MAXNB];
    __shared__ int incl[MAXNB];
    __shared__ int cntA[MAXNB];
    __shared__ int gbase[MAXNB];
    const int tid = threadIdx.x;

    scnt[tid] = 0;  // BIN_THREADS == MAXNB
    __syncthreads();

    // int4-vectorized: each thread owns 8 consecutive edges (2 x int4)
    const int base = blockIdx.x * TILE + tid * 8;
#pragma unroll
    for (int q = 0; q < 2; ++q) {
        const int eb = base + q * 4;
        if (eb + 3 < E) {
            const int4 iv = *(const int4*)(iInd + eb);
            const int4 jv = *(const int4*)(jInd + eb);
            const int is[4] = {iv.x, iv.y, iv.z, iv.w};
            const int js[4] = {jv.x, jv.y, jv.z, jv.w};
#pragma unroll
            for (int k = 0; k < 4; ++k) {
                const int i = is[k], j = js[k];
                const int b = i >> BSHIFT;
                const int slot = atomicAdd(&scnt[b], 1);
                if (slot < SLOTS)
                    stage[b * SLOTS + slot] = ((i & (BNODES - 1)) << 16) | j;
                else
                    push_ovf(ovf_cnt, ovf, ovf_cap, i, j);
            }
        } else {
            for (int k = 0; k < 4; ++k) {
                const int e = eb + k;
                if (e < E) {
                    const int i = iInd[e], j = jInd[e];
                    const int b = i >> BSHIFT;
                    const int slot = atomicAdd(&scnt[b], 1);
                    if (slot < SLOTS)
                        stage[b * SLOTS + slot] =
                            ((i & (BNODES - 1)) << 16) | j;
                    else
                        push_ovf(ovf_cnt, ovf, ovf_cap, i, j);
                }
            }
        }
    }
    __syncthreads();

    int c_b = (tid < NB) ? min(scnt[tid], SLOTS) : 0;
    cntA[tid] = c_b;
    incl[tid] = c_b;
    __syncthreads();
    for (int off = 1; off < MAXNB; off <<= 1) {
        const int v = (tid >= off) ? incl[tid - off] : 0;
        __syncthreads();
        incl[tid] += v;
        __syncthreads();
    }
    if (tid < NB && c_b > 0) gbase[tid] = atomicAdd(&gcursor[tid], c_b);
    __syncthreads();

    const int total = incl[MAXNB - 1];
    for (int idx = tid; idx < total; idx += BIN_THREADS) {
        int lo = 0, hi = MAXNB - 1;
        while (lo < hi) {
            const int mid = (lo + hi) >> 1;
            if (incl[mid] > idx) hi = mid; else lo = mid + 1;
        }
        const int b = lo;
        const int k = idx - (incl[b] - cntA[b]);
        const int rec = stage[b * SLOTS + k];
        const int gslot = gbase[b] + k;
        if (gslot < cap) {
            bins[(size_t)b * cap + gslot] = rec;
        } else {
            push_ovf(ovf_cnt, ovf, ovf_cap,
                     (b << BSHIFT) | (rec >> 16), rec & 0xFFFF);
        }
    }
}

// NB*4 blocks; block (bucket, sub) owns nodes [sub*32, sub*32+32).
__global__ __launch_bounds__(SR_THREADS) void sort_reduce3(
    const int* __restrict__ bins, const int* __restrict__ gcursor,
    const unsigned short* __restrict__ xtb, const float* __restrict__ W,
    float* __restrict__ out, int* __restrict__ ovf_cnt,
    int2* __restrict__ ovf, int ovf_cap, int N, int cap) {
    const int bucket = blockIdx.x >> 2;
    const int sub = blockIdx.x & (SPLIT2 - 1);
    __shared__ unsigned short sj[SJ2_CAP];
    __shared__ float acc[NSUB * 33];
    __shared__ int hcnt[NSUB];
    __shared__ int off[NSUB + 1];
    __shared__ int cur[NSUB];

    int cnt = gcursor[bucket];
    if (cnt > cap) cnt = cap;
    const int* rec = bins + (size_t)bucket * cap;

    if (threadIdx.x < NSUB) { hcnt[threadIdx.x] = 0; cur[threadIdx.x] = 0; }
    __syncthreads();

    // pass 1: histogram of in-range il
    for (int r = threadIdx.x; r < cnt; r += SR_THREADS) {
        const int il = rec[r] >> 16;
        if ((il >> 5) == sub) atomicAdd(&hcnt[il & (NSUB - 1)], 1);
    }
    __syncthreads();

    if (threadIdx.x == 0) {
        int run = 0;
        for (int k = 0; k < NSUB; ++k) { off[k] = run; run += hcnt[k]; }
        off[NSUB] = run;
    }
    __syncthreads();

    // pass 2: scatter in-range j into sorted order
    for (int r = threadIdx.x; r < cnt; r += SR_THREADS) {
        const int pr = rec[r];
        const int il = pr >> 16;
        if ((il >> 5) == sub) {
            const int pos = off[il & (NSUB - 1)] +
                            atomicAdd(&cur[il & (NSUB - 1)], 1);
            if (pos < SJ2_CAP) {
                sj[pos] = (unsigned short)(pr & 0xFFFF);
            } else {
                push_ovf(ovf_cnt, ovf, ovf_cap,
                         (bucket << BSHIFT) | il, pr & 0xFFFF);
            }
        }
    }
    __syncthreads();

    // register segment-sum: 16 groups x 32 lanes.
    // Within a group: rslot = lane>>3 (4 records in flight), c4 = (lane&7)*4
    // (4 channels per lane, uint2 = 8B load). 4 records / group-VMEM-instr.
    const int lane = threadIdx.x & 31;
    const int g = threadIdx.x >> 5;
    const int rslot = lane >> 3;
    const int c4 = (lane & 7) * 4;
    for (int ill = g; ill < NSUB; ill += SR_THREADS / 32) {
        const int beg = min(off[ill], SJ2_CAP);
        const int end = min(off[ill + 1], SJ2_CAP);
        float a0 = 0.f, a1 = 0.f, a2 = 0.f, a3 = 0.f;
        int rb = beg;
        for (; rb + 8 <= end; rb += 8) {       // 2 batches in flight
            const int j0 = sj[rb + rslot];
            const int j1 = sj[rb + 4 + rslot];
            const uint2 u0 = *(const uint2*)(xtb + (size_t)j0 * TCH + c4);
            const uint2 u1 = *(const uint2*)(xtb + (size_t)j1 * TCH + c4);
            a0 += __uint_as_float(u0.x << 16);
            a1 += __uint_as_float(u0.x & 0xFFFF0000u);
            a2 += __uint_as_float(u0.y << 16);
            a3 += __uint_as_float(u0.y & 0xFFFF0000u);
            a0 += __uint_as_float(u1.x << 16);
            a1 += __uint_as_float(u1.x & 0xFFFF0000u);
            a2 += __uint_as_float(u1.y << 16);
            a3 += __uint_as_float(u1.y & 0xFFFF0000u);
        }
        {
            const int rr = rb + rslot;
            if (rr < end) {
                const int j = sj[rr];
                const uint2 u = *(const uint2*)(xtb + (size_t)j * TCH + c4);
                a0 += __uint_as_float(u.x << 16);
                a1 += __uint_as_float(u.x & 0xFFFF0000u);
                a2 += __uint_as_float(u.y << 16);
                a3 += __uint_as_float(u.y & 0xFFFF0000u);
            }
            const int rr2 = rb + 4 + rslot;
            if (rr2 < end) {
                const int j = sj[rr2];
                const uint2 u = *(const uint2*)(xtb + (size_t)j * TCH + c4);
                a0 += __uint_as_float(u.x << 16);
                a1 += __uint_as_float(u.x & 0xFFFF0000u);
                a2 += __uint_as_float(u.y << 16);
                a3 += __uint_as_float(u.y & 0xFFFF0000u);
            }
        }
        // combine the 4 record slots (lanes differing in bits 3,4)
        a0 += __shfl_xor(a0, 8);  a1 += __shfl_xor(a1, 8);
        a2 += __shfl_xor(a2, 8);  a3 += __shfl_xor(a3, 8);
        a0 += __shfl_xor(a0, 16); a1 += __shfl_xor(a1, 16);
        a2 += __shfl_xor(a2, 16); a3 += __shfl_xor(a3, 16);
        if (rslot == 0) {
            float* ap = &acc[ill * 33 + c4];
            ap[0] = a0; ap[1] = a1; ap[2] = a2; ap[3] = a3;
        }
    }
    __syncthreads();

    // exclusive-owner plain coalesced store
    const int i0 = (bucket << BSHIFT) + sub * NSUB;
    for (int k = threadIdx.x; k < NSUB * TCH; k += SR_THREADS) {
        const int ill = k & (NSUB - 1);
        const int cc = k >> 5;
        const int i = i0 + ill;
        if (i < N) {
            const float w = W[i];
            out[(size_t)cc * N + i] = w * w * acc[ill * 33 + cc];
        }
    }
}

// applies overflow entries (normally zero) with atomics, AFTER sort_reduce3.
__global__ void overflow_apply(const int2* __restrict__ ovf,
                               const int* __restrict__ ovf_cnt,
                               const float* __restrict__ W,
                               const float* __restrict__ x,
                               float* __restrict__ out, int N, int ovf_cap) {
    int cnt = *ovf_cnt;
    if (cnt > ovf_cap) cnt = ovf_cap;
    const long long total = (long long)cnt * TCH;
    const long long stride = (long long)gridDim.x * blockDim.x;
    for (long long t = (long long)blockIdx.x * blockDim.x + threadIdx.x;
         t < total; t += stride) {
        const int e = (int)(t >> 5);
        const int c = (int)(t & 31);
        const int2 p = ovf[e];
        const float w = W[p.x];
        atomicAdd(&out[(size_t)c * N + p.x], w * w * x[(size_t)c * N + p.y]);
    }
}

// ---- fallback (ws too small / N too big for record packing) ----
__global__ void edge_scatter_cn(const int* __restrict__ iInd,
                                const int* __restrict__ jInd,
                                const float* __restrict__ W,
                                const float* __restrict__ x,
                                float* __restrict__ out, int E, int N) {
    const long long t = (long long)blockIdx.x * blockDim.x + threadIdx.x;
    const int e = (int)(t >> 5);
    const int c = (int)(t & 31);
    if (e < E) {
        const int i = iInd[e];
        const int j = jInd[e];
        const float w = W[i];
        atomicAdd(&out[(size_t)c * N + i], w * w * x[(size_t)c * N + j]);
    }
}

extern "C" void kernel_launch(void* const* d_in, const int* in_sizes, int n_in,
                              void* d_out, int out_size, void* d_ws, size_t ws_size,
                              hipStream_t stream) {
    const float* x    = (const float*)d_in[0];   // [1, C, N]
    const float* W    = (const float*)d_in[1];   // [N]
    const int*   iInd = (const int*)d_in[2];     // [E]
    const int*   jInd = (const int*)d_in[3];     // [E]

    const int N = in_sizes[1];
    const int E = in_sizes[2];
    float* out = (float*)d_out;

    const int NB = (N + BNODES - 1) >> BSHIFT;
    const int mean = (NB > 0) ? (E / NB) : 0;
    const int cap = mean + (int)(8.0 * sqrt((double)(mean > 0 ? mean : 1))) + 64;

    // ws layout (256B-aligned): xtb | bins | gcursor(NB)+ovf_cnt(1) | ovf
    const size_t A = 256;
    const size_t xtb_bytes = (((size_t)N * TCH * 2) + A - 1) / A * A;
    const size_t bin_bytes = (((size_t)NB * cap * 4) + A - 1) / A * A;
    const size_t cur_bytes = (((size_t)(NB + 1) * 4) + A - 1) / A * A;
    const size_t base_need = xtb_bytes + bin_bytes + cur_bytes;

    int ovf_cap = 0;
    if (ws_size > base_need) {
        size_t avail = ws_size - base_need;
        size_t oc = avail / sizeof(int2);
        if (oc > (size_t)(1 << 21)) oc = (size_t)(1 << 21);
        ovf_cap = (int)oc;
    }

    if (ws_size >= base_need && ovf_cap >= 65536 && NB <= MAXNB && N <= 65536) {
        char* wsb = (char*)d_ws;
        unsigned short* xtb = (unsigned short*)wsb;
        int*   bins    = (int*)(wsb + xtb_bytes);
        int*   gcursor = (int*)(wsb + xtb_bytes + bin_bytes);
        int*   ovf_cnt = gcursor + NB;
        int2*  ovf     = (int2*)(wsb + base_need);

        init_counters<<<1, 512, 0, stream>>>(gcursor, NB);

        const int ntiles = (N + 31) / 32;
        dim3 tb(32, 32);
        transpose_CN_to_NC_bf16<<<ntiles, tb, 0, stream>>>(x, xtb, N);

        const int bin_blocks = (E + TILE - 1) / TILE;
        bin_edges<<<bin_blocks, BIN_THREADS, 0, stream>>>(
            iInd, jInd, bins, gcursor, ovf_cnt, ovf, ovf_cap, E, NB, cap);

        sort_reduce3<<<NB * SPLIT2, SR_THREADS, 0, stream>>>(
            bins, gcursor, xtb, W, out, ovf_cnt, ovf, ovf_cap, N, cap);

        overflow_apply<<<128, 256, 0, stream>>>(
            ovf, ovf_cnt, W, x, out, N, ovf_cap);
    } else {
        hipMemsetAsync(out, 0, (size_t)out_size * sizeof(float), stream);
        const int threads = 256;
        const long long total = (long long)E * TCH;
        const int blocks = (int)((total + threads - 1) / threads);
        edge_scatter_cn<<<blocks, threads, 0, stream>>>(iInd, jInd, W, x, out, E, N);
    }
}